// Round 3
// baseline (402.952 us; speedup 1.0000x reference)
//
#include <hip/hip_runtime.h>
#include <hip/hip_bf16.h>
#include <cstdint>
#include <cstddef>

// YatDense: out[m,n] = (y^2 / (|x_m|^2 + |w_n|^2 - 2y + eps)) * scale + bias[n]
//   y = x[m,:] . w[n,:]   GEMM M=16384, N=2048, K=2048 (B^T layout input)
//   scale = (sqrt(F)/log(1+F))^alpha
// Inputs fp32, OUTPUT fp32 (reference dtype). Round-2 evidence: writing bf16
// filled only half the out buffer -> absmax = second-half ref max. Pipeline:
// prep converts x,w -> bf16 into d_ws + exact fp32 row norms; m97-structure
// bf16 MFMA GEMM (fp32 accum) + fused Yat epilogue, fp32 stores.

typedef __bf16 bf16_t;
typedef __bf16 bf16x8 __attribute__((ext_vector_type(8)));
typedef __bf16 bf16x4 __attribute__((ext_vector_type(4)));
typedef float f32x4 __attribute__((ext_vector_type(4)));

constexpr int M_DIM = 16384;  // B*S
constexpr int N_DIM = 2048;   // F
constexpr int K_DIM = 2048;   // D
constexpr int BM = 128, BN = 128, BK = 32;
constexpr int KITERS = K_DIM / BK;  // 64

__device__ __forceinline__ void async16(const bf16_t* g, bf16_t* l) {
    __builtin_amdgcn_global_load_lds(
        (const __attribute__((address_space(1))) void*)g,
        (__attribute__((address_space(3))) void*)l,
        16, 0, 0);
}

// ---------------------------------------------------------------------------
// prep: one block per row (x rows [0,M), w rows [M,M+N)).
// Reads 2048 fp32, writes 2048 bf16 (RNE), computes fp32 sum of squares.
// ---------------------------------------------------------------------------
__global__ __launch_bounds__(256) void prep_convert(const float* __restrict__ x,
                                                    const float* __restrict__ w,
                                                    bf16_t* __restrict__ xb,
                                                    bf16_t* __restrict__ wb,
                                                    float* __restrict__ xsq,
                                                    float* __restrict__ wsq) {
    const int row = blockIdx.x;
    const float* src;
    bf16_t* dstb;
    float* dsts;
    if (row < M_DIM) {
        src = x + (size_t)row * K_DIM;
        dstb = xb + (size_t)row * K_DIM;
        dsts = xsq + row;
    } else {
        const int r = row - M_DIM;
        src = w + (size_t)r * K_DIM;
        dstb = wb + (size_t)r * K_DIM;
        dsts = wsq + r;
    }
    const float4* s4 = (const float4*)src;
    const float4 a = s4[threadIdx.x];
    const float4 b = s4[threadIdx.x + 256];
    float s = a.x * a.x + a.y * a.y + a.z * a.z + a.w * a.w
            + b.x * b.x + b.y * b.y + b.z * b.z + b.w * b.w;
    bf16x4 av = { (bf16_t)a.x, (bf16_t)a.y, (bf16_t)a.z, (bf16_t)a.w };
    bf16x4 bv = { (bf16_t)b.x, (bf16_t)b.y, (bf16_t)b.z, (bf16_t)b.w };
    ((bf16x4*)dstb)[threadIdx.x] = av;
    ((bf16x4*)dstb)[threadIdx.x + 256] = bv;
#pragma unroll
    for (int off = 32; off > 0; off >>= 1) s += __shfl_down(s, off, 64);
    __shared__ float red[4];
    const int lane = threadIdx.x & 63;
    const int wv = threadIdx.x >> 6;
    if (lane == 0) red[wv] = s;
    __syncthreads();
    if (threadIdx.x == 0) *dsts = red[0] + red[1] + red[2] + red[3];
}

// ---------------------------------------------------------------------------
// GEMM + Yat epilogue. m97 structure: 128x128 tile, BK=32, 256 threads,
// 4 waves in 2x2, each wave 4x4 fragments of mfma_f32_16x16x32_bf16,
// global->LDS staging via global_load_lds width=16. fp32 epilogue stores.
// ---------------------------------------------------------------------------
__global__ __launch_bounds__(256) void yat_gemm(const bf16_t* __restrict__ A,   // [M,K] bf16 (ws)
                                                const bf16_t* __restrict__ Bw,  // [N,K] bf16 (ws)
                                                const float* __restrict__ xsq,  // [M]
                                                const float* __restrict__ wsq,  // [N]
                                                const float* __restrict__ bias,   // [N] fp32
                                                const float* __restrict__ alpha,  // [1] fp32
                                                float* __restrict__ out) {        // [M,N] fp32
    __shared__ bf16_t As[BM * BK];  // 8 KB
    __shared__ bf16_t Bs[BN * BK];  // 8 KB

    const int tid = threadIdx.x;
    const int lane = tid & 63;
    const int wv = tid >> 6;
    const int wm = wv >> 1;
    const int wn = wv & 1;

    const int bm = (int)blockIdx.x >> 4;  // 0..127
    const int bn = (int)blockIdx.x & 15;  // 0..15

    // staging: lane loads 16 B (8 bf16 along K); wave wv covers rows
    // [wv*16, wv*16+16) and +64. LDS dest = wave-uniform base + lane*16.
    const int srow = wv * 16 + (lane >> 2);
    const int scol = (lane & 3) * 8;
    const bf16_t* Ag = A + ((size_t)(bm * BM + srow)) * K_DIM + scol;
    const bf16_t* Bg = Bw + ((size_t)(bn * BN + srow)) * K_DIM + scol;
    bf16_t* ldsA = As + srow * BK + scol;
    bf16_t* ldsB = Bs + srow * BK + scol;

    // 16x16x32 fragment addressing:
    //  A: lane holds A[m=lane&15][k=(lane>>4)*8+j]; B mirrored ([n][k] in Bs)
    //  C/D: col=lane&15, row=(lane>>4)*4+reg   [m89/m91-verified]
    const int frm = lane & 15;
    const int frk = (lane >> 4) * 8;

    f32x4 acc[4][4] = {};

    for (int kt = 0; kt < KITERS; ++kt) {
        const int k0 = kt * BK;
        async16(Ag + k0, ldsA);
        async16(Ag + k0 + (size_t)64 * K_DIM, ldsA + 64 * BK);
        async16(Bg + k0, ldsB);
        async16(Bg + k0 + (size_t)64 * K_DIM, ldsB + 64 * BK);
        __syncthreads();

        bf16x8 af[4], bv[4];
#pragma unroll
        for (int i = 0; i < 4; ++i)
            af[i] = *(const bf16x8*)&As[(wm * 64 + i * 16 + frm) * BK + frk];
#pragma unroll
        for (int j = 0; j < 4; ++j)
            bv[j] = *(const bf16x8*)&Bs[(wn * 64 + j * 16 + frm) * BK + frk];
#pragma unroll
        for (int i = 0; i < 4; ++i)
#pragma unroll
            for (int j = 0; j < 4; ++j)
                acc[i][j] = __builtin_amdgcn_mfma_f32_16x16x32_bf16(af[i], bv[j], acc[i][j], 0, 0, 0);
        __syncthreads();
    }

    // epilogue (fp32 stores)
    const float sc = powf(sqrtf((float)N_DIM) / logf(1.0f + (float)N_DIM), alpha[0]);
    float wsq_c[4], bias_c[4];
#pragma unroll
    for (int j = 0; j < 4; ++j) {
        const int col = bn * BN + wn * 64 + j * 16 + frm;
        wsq_c[j] = wsq[col];
        bias_c[j] = bias[col];
    }
#pragma unroll
    for (int i = 0; i < 4; ++i) {
#pragma unroll
        for (int r = 0; r < 4; ++r) {
            const int row = bm * BM + wm * 64 + i * 16 + (lane >> 4) * 4 + r;
            const float xs = xsq[row];
            float* orow = out + (size_t)row * N_DIM + bn * BN + wn * 64 + frm;
#pragma unroll
            for (int j = 0; j < 4; ++j) {
                const float y = acc[i][j][r];
                const float d = xs + wsq_c[j] - 2.0f * y + 1e-6f;
                orow[j * 16] = (y * y) / d * sc + bias_c[j];
            }
        }
    }
}

extern "C" void kernel_launch(void* const* d_in, const int* in_sizes, int n_in,
                              void* d_out, int out_size, void* d_ws, size_t ws_size,
                              hipStream_t stream) {
    (void)in_sizes; (void)n_in; (void)out_size; (void)ws_size;
    const float* x = (const float*)d_in[0];      // [16384, 2048] fp32
    const float* w = (const float*)d_in[1];      // [2048, 2048] fp32
    const float* alpha = (const float*)d_in[2];  // [1] fp32
    const float* bias = (const float*)d_in[3];   // [2048] fp32
    float* out = (float*)d_out;                  // [16384, 2048] fp32

    // ws layout: xb (33.5M bf16), wb (4.2M bf16), xsq (16384 f32), wsq (2048 f32)
    bf16_t* xb = (bf16_t*)d_ws;
    bf16_t* wb = xb + (size_t)M_DIM * K_DIM;
    float* xsq = (float*)(wb + (size_t)N_DIM * K_DIM);
    float* wsq = xsq + M_DIM;

    prep_convert<<<M_DIM + N_DIM, 256, 0, stream>>>(x, w, xb, wb, xsq, wsq);
    yat_gemm<<<(M_DIM / BM) * (N_DIM / BN), 256, 0, stream>>>(xb, wb, xsq, wsq, bias, alpha, out);
}

// Round 4
// 396.009 us; speedup vs baseline: 1.0175x; 1.0175x over previous
//
#include <hip/hip_runtime.h>
#include <hip/hip_bf16.h>
#include <cstdint>
#include <cstddef>

// YatDense: out[m,n] = (y^2 / (|x_m|^2 + |w_n|^2 - 2y + eps)) * scale + bias[n]
//   y = x[m,:] . w[n,:]   GEMM M=16384, N=2048, K=2048 (B^T layout input)
// Inputs fp32, output fp32. prep converts x,w -> bf16 (d_ws) + exact fp32 row
// norms; m97-structure bf16 MFMA GEMM + fused Yat epilogue.
// R4 changes: (1) XOR bank-swizzle of LDS K-chunks (kills the +4cyc/b128
// conflict penalty; staging LDS dest stays base+lane*16 — only the global
// source column is permuted per lane); (2) XCD-aware block remap so the 16
// blocks sharing an A panel land on one XCD's L2.

typedef __bf16 bf16_t;
typedef __bf16 bf16x8 __attribute__((ext_vector_type(8)));
typedef __bf16 bf16x4 __attribute__((ext_vector_type(4)));
typedef float f32x4 __attribute__((ext_vector_type(4)));

constexpr int M_DIM = 16384;  // B*S
constexpr int N_DIM = 2048;   // F
constexpr int K_DIM = 2048;   // D
constexpr int BM = 128, BN = 128, BK = 32;
constexpr int KITERS = K_DIM / BK;  // 64

__device__ __forceinline__ void async16(const bf16_t* g, bf16_t* l) {
    __builtin_amdgcn_global_load_lds(
        (const __attribute__((address_space(1))) void*)g,
        (__attribute__((address_space(3))) void*)l,
        16, 0, 0);
}

// ---------------------------------------------------------------------------
// prep: one block per row (x rows [0,M), w rows [M,M+N)).
// Reads 2048 fp32, writes 2048 bf16 (RNE), computes fp32 sum of squares.
// ---------------------------------------------------------------------------
__global__ __launch_bounds__(256) void prep_convert(const float* __restrict__ x,
                                                    const float* __restrict__ w,
                                                    bf16_t* __restrict__ xb,
                                                    bf16_t* __restrict__ wb,
                                                    float* __restrict__ xsq,
                                                    float* __restrict__ wsq) {
    const int row = blockIdx.x;
    const float* src;
    bf16_t* dstb;
    float* dsts;
    if (row < M_DIM) {
        src = x + (size_t)row * K_DIM;
        dstb = xb + (size_t)row * K_DIM;
        dsts = xsq + row;
    } else {
        const int r = row - M_DIM;
        src = w + (size_t)r * K_DIM;
        dstb = wb + (size_t)r * K_DIM;
        dsts = wsq + r;
    }
    const float4* s4 = (const float4*)src;
    const float4 a = s4[threadIdx.x];
    const float4 b = s4[threadIdx.x + 256];
    float s = a.x * a.x + a.y * a.y + a.z * a.z + a.w * a.w
            + b.x * b.x + b.y * b.y + b.z * b.z + b.w * b.w;
    bf16x4 av = { (bf16_t)a.x, (bf16_t)a.y, (bf16_t)a.z, (bf16_t)a.w };
    bf16x4 bv = { (bf16_t)b.x, (bf16_t)b.y, (bf16_t)b.z, (bf16_t)b.w };
    ((bf16x4*)dstb)[threadIdx.x] = av;
    ((bf16x4*)dstb)[threadIdx.x + 256] = bv;
#pragma unroll
    for (int off = 32; off > 0; off >>= 1) s += __shfl_down(s, off, 64);
    __shared__ float red[4];
    const int lane = threadIdx.x & 63;
    const int wv = threadIdx.x >> 6;
    if (lane == 0) red[wv] = s;
    __syncthreads();
    if (threadIdx.x == 0) *dsts = red[0] + red[1] + red[2] + red[3];
}

// ---------------------------------------------------------------------------
// GEMM + Yat epilogue. 128x128 tile, BK=32, 256 threads, 4 waves 2x2, each
// wave 4x4 frags of mfma_f32_16x16x32_bf16, global_load_lds width=16 staging.
// LDS layout swizzle: physical chunk c of row r holds global K-chunk
// c ^ ((r>>1)&3)  (chunk = 8 bf16 = 16 B). Fragment read for chunk j of row r
// reads physical chunk j ^ ((r>>1)&3) -> every 8-lane phase of ds_read_b128
// covers all 32 banks (conflict-free).
// ---------------------------------------------------------------------------
__global__ __launch_bounds__(256) void yat_gemm(const bf16_t* __restrict__ A,   // [M,K] bf16 (ws)
                                                const bf16_t* __restrict__ Bw,  // [N,K] bf16 (ws)
                                                const float* __restrict__ xsq,  // [M]
                                                const float* __restrict__ wsq,  // [N]
                                                const float* __restrict__ bias,   // [N] fp32
                                                const float* __restrict__ alpha,  // [1] fp32
                                                float* __restrict__ out) {        // [M,N] fp32
    __shared__ bf16_t As[BM * BK];  // 8 KB
    __shared__ bf16_t Bs[BN * BK];  // 8 KB

    const int tid = threadIdx.x;
    const int lane = tid & 63;
    const int wv = tid >> 6;
    const int wm = wv >> 1;
    const int wn = wv & 1;

    // XCD-aware remap (assumes xcd = blockIdx % 8 round-robin): all 16 blocks
    // sharing bm land on one XCD; bn sweeps fastest within the XCD sequence.
    const int blk = (int)blockIdx.x;
    const int o = blk >> 3;
    const int bm = (blk & 7) * 16 + (o >> 4);  // 0..127
    const int bn = o & 15;                     // 0..15

    // staging: lane's LDS dest byte = wave_base + lane*16 (HW requirement).
    // lane covers (srow = wv*16 + lane>>2, physical chunk c = lane&3);
    // it must hold global chunk c ^ s(srow), s(r) = (r>>1)&3 = (lane>>3)&3.
    const int srow = wv * 16 + (lane >> 2);
    const int gch = (lane & 3) ^ ((lane >> 3) & 3);
    const bf16_t* Ag = A + ((size_t)(bm * BM + srow)) * K_DIM + gch * 8;
    const bf16_t* Bg = Bw + ((size_t)(bn * BN + srow)) * K_DIM + gch * 8;
    bf16_t* ldsA = As + srow * BK + (lane & 3) * 8;
    bf16_t* ldsB = Bs + srow * BK + (lane & 3) * 8;

    // 16x16x32 fragment addressing:
    //  A: lane holds A[m=lane&15][k=(lane>>4)*8+j]; B mirrored ([n][k] in Bs)
    //  C/D: col=lane&15, row=(lane>>4)*4+reg   [m89/m91-verified]
    const int frm = lane & 15;
    const int jch = lane >> 4;            // K-chunk 0..3
    const int sw = (lane >> 1) & 3;       // = ((row within 16)>>1)&3
    const int choff = ((jch ^ sw) * 8);   // swizzled physical chunk offset

    f32x4 acc[4][4] = {};

    for (int kt = 0; kt < KITERS; ++kt) {
        const int k0 = kt * BK;
        async16(Ag + k0, ldsA);
        async16(Ag + k0 + (size_t)64 * K_DIM, ldsA + 64 * BK);
        async16(Bg + k0, ldsB);
        async16(Bg + k0 + (size_t)64 * K_DIM, ldsB + 64 * BK);
        __syncthreads();

        bf16x8 af[4], bv[4];
#pragma unroll
        for (int i = 0; i < 4; ++i)
            af[i] = *(const bf16x8*)&As[(wm * 64 + i * 16 + frm) * BK + choff];
#pragma unroll
        for (int j = 0; j < 4; ++j)
            bv[j] = *(const bf16x8*)&Bs[(wn * 64 + j * 16 + frm) * BK + choff];
#pragma unroll
        for (int i = 0; i < 4; ++i)
#pragma unroll
            for (int j = 0; j < 4; ++j)
                acc[i][j] = __builtin_amdgcn_mfma_f32_16x16x32_bf16(af[i], bv[j], acc[i][j], 0, 0, 0);
        __syncthreads();
    }

    // epilogue (fp32 stores)
    const float sc = powf(sqrtf((float)N_DIM) / logf(1.0f + (float)N_DIM), alpha[0]);
    float wsq_c[4], bias_c[4];
#pragma unroll
    for (int j = 0; j < 4; ++j) {
        const int col = bn * BN + wn * 64 + j * 16 + frm;
        wsq_c[j] = wsq[col];
        bias_c[j] = bias[col];
    }
#pragma unroll
    for (int i = 0; i < 4; ++i) {
#pragma unroll
        for (int r = 0; r < 4; ++r) {
            const int row = bm * BM + wm * 64 + i * 16 + (lane >> 4) * 4 + r;
            const float xs = xsq[row];
            float* orow = out + (size_t)row * N_DIM + bn * BN + wn * 64 + frm;
#pragma unroll
            for (int j = 0; j < 4; ++j) {
                const float y = acc[i][j][r];
                const float d = xs + wsq_c[j] - 2.0f * y + 1e-6f;
                orow[j * 16] = (y * y) / d * sc + bias_c[j];
            }
        }
    }
}

extern "C" void kernel_launch(void* const* d_in, const int* in_sizes, int n_in,
                              void* d_out, int out_size, void* d_ws, size_t ws_size,
                              hipStream_t stream) {
    (void)in_sizes; (void)n_in; (void)out_size; (void)ws_size;
    const float* x = (const float*)d_in[0];      // [16384, 2048] fp32
    const float* w = (const float*)d_in[1];      // [2048, 2048] fp32
    const float* alpha = (const float*)d_in[2];  // [1] fp32
    const float* bias = (const float*)d_in[3];   // [2048] fp32
    float* out = (float*)d_out;                  // [16384, 2048] fp32

    // ws layout: xb (33.5M bf16), wb (4.2M bf16), xsq (16384 f32), wsq (2048 f32)
    bf16_t* xb = (bf16_t*)d_ws;
    bf16_t* wb = xb + (size_t)M_DIM * K_DIM;
    float* xsq = (float*)(wb + (size_t)N_DIM * K_DIM);
    float* wsq = xsq + M_DIM;

    prep_convert<<<M_DIM + N_DIM, 256, 0, stream>>>(x, w, xb, wb, xsq, wsq);
    yat_gemm<<<(M_DIM / BM) * (N_DIM / BN), 256, 0, stream>>>(xb, wb, xsq, wsq, bias, alpha, out);
}

// Round 5
// 383.019 us; speedup vs baseline: 1.0520x; 1.0339x over previous
//
#include <hip/hip_runtime.h>
#include <hip/hip_bf16.h>
#include <cstdint>
#include <cstddef>

// YatDense: out[m,n] = (y^2 / (|x_m|^2 + |w_n|^2 - 2y + eps)) * scale + bias[n]
//   y = x[m,:] . w[n,:]   GEMM M=16384, N=2048, K=2048 (B^T layout input)
// Inputs fp32, output fp32. prep converts x,w -> bf16 (d_ws) + exact fp32 row
// norms; bf16 MFMA GEMM + fused Yat epilogue.
// R5: tile 256x128, 512 threads (8 waves 4x2), grid=1024 -> 4 blocks/CU of
// work, 2 resident (r4 showed 1 block/CU kills the implicit overlap that the
// m97 structure relies on: conflicts=0 + FETCH halved yet dur rose).
// Keep XOR LDS swizzle (conflicts 1.68e7 -> 0); revert XCD remap (regressed).

typedef __bf16 bf16_t;
typedef __bf16 bf16x8 __attribute__((ext_vector_type(8)));
typedef __bf16 bf16x4 __attribute__((ext_vector_type(4)));
typedef float f32x4 __attribute__((ext_vector_type(4)));

constexpr int M_DIM = 16384;  // B*S
constexpr int N_DIM = 2048;   // F
constexpr int K_DIM = 2048;   // D
constexpr int BM = 256, BN = 128, BK = 32;
constexpr int KITERS = K_DIM / BK;  // 64

__device__ __forceinline__ void async16(const bf16_t* g, bf16_t* l) {
    __builtin_amdgcn_global_load_lds(
        (const __attribute__((address_space(1))) void*)g,
        (__attribute__((address_space(3))) void*)l,
        16, 0, 0);
}

// ---------------------------------------------------------------------------
// prep: one block per row (x rows [0,M), w rows [M,M+N)).
// Reads 2048 fp32, writes 2048 bf16 (RNE), computes fp32 sum of squares.
// ---------------------------------------------------------------------------
__global__ __launch_bounds__(256) void prep_convert(const float* __restrict__ x,
                                                    const float* __restrict__ w,
                                                    bf16_t* __restrict__ xb,
                                                    bf16_t* __restrict__ wb,
                                                    float* __restrict__ xsq,
                                                    float* __restrict__ wsq) {
    const int row = blockIdx.x;
    const float* src;
    bf16_t* dstb;
    float* dsts;
    if (row < M_DIM) {
        src = x + (size_t)row * K_DIM;
        dstb = xb + (size_t)row * K_DIM;
        dsts = xsq + row;
    } else {
        const int r = row - M_DIM;
        src = w + (size_t)r * K_DIM;
        dstb = wb + (size_t)r * K_DIM;
        dsts = wsq + r;
    }
    const float4* s4 = (const float4*)src;
    const float4 a = s4[threadIdx.x];
    const float4 b = s4[threadIdx.x + 256];
    float s = a.x * a.x + a.y * a.y + a.z * a.z + a.w * a.w
            + b.x * b.x + b.y * b.y + b.z * b.z + b.w * b.w;
    bf16x4 av = { (bf16_t)a.x, (bf16_t)a.y, (bf16_t)a.z, (bf16_t)a.w };
    bf16x4 bv = { (bf16_t)b.x, (bf16_t)b.y, (bf16_t)b.z, (bf16_t)b.w };
    ((bf16x4*)dstb)[threadIdx.x] = av;
    ((bf16x4*)dstb)[threadIdx.x + 256] = bv;
#pragma unroll
    for (int off = 32; off > 0; off >>= 1) s += __shfl_down(s, off, 64);
    __shared__ float red[4];
    const int lane = threadIdx.x & 63;
    const int wv = threadIdx.x >> 6;
    if (lane == 0) red[wv] = s;
    __syncthreads();
    if (threadIdx.x == 0) *dsts = red[0] + red[1] + red[2] + red[3];
}

// ---------------------------------------------------------------------------
// GEMM + Yat epilogue. 256x128 tile, BK=32, 512 threads (8 waves in 4x2),
// each wave 4x4 frags of mfma_f32_16x16x32_bf16, global_load_lds width=16.
// LDS swizzle: physical 16B chunk c of row r holds global K-chunk
// c ^ ((r>>1)&3); fragment read for chunk j of row r reads j ^ ((r>>1)&3)
// -> every 8-lane phase of ds_read_b128 covers all 32 banks (0 conflicts, r4).
// ---------------------------------------------------------------------------
__global__ __launch_bounds__(512, 4) void yat_gemm(const bf16_t* __restrict__ A,   // [M,K] bf16 (ws)
                                                   const bf16_t* __restrict__ Bw,  // [N,K] bf16 (ws)
                                                   const float* __restrict__ xsq,  // [M]
                                                   const float* __restrict__ wsq,  // [N]
                                                   const float* __restrict__ bias,   // [N] fp32
                                                   const float* __restrict__ alpha,  // [1] fp32
                                                   float* __restrict__ out) {        // [M,N] fp32
    __shared__ bf16_t As[BM * BK];  // 16 KB
    __shared__ bf16_t Bs[BN * BK];  // 8 KB

    const int tid = threadIdx.x;
    const int lane = tid & 63;
    const int wv = tid >> 6;   // 0..7
    const int wm = wv >> 1;    // 0..3 : wave row (64-row band)
    const int wn = wv & 1;     // 0..1 : wave col (64-col band)

    const int bm = (int)blockIdx.x >> 4;  // 0..63
    const int bn = (int)blockIdx.x & 15;  // 0..15

    // staging: lane's LDS dest byte = wave_base + lane*16 (HW requirement).
    // Per async16 a wave covers 16 rows (4 lanes/row). A: rows wv*16+(0..15)
    // and +128; B: rows wv*16+(0..15). Global source chunk is XOR-permuted.
    const int srow = wv * 16 + (lane >> 2);
    const int gch = (lane & 3) ^ ((lane >> 3) & 3);  // swizzled global chunk
    const bf16_t* Ag = A + ((size_t)(bm * BM + srow)) * K_DIM + gch * 8;
    const bf16_t* Bg = Bw + ((size_t)(bn * BN + srow)) * K_DIM + gch * 8;
    bf16_t* ldsA = As + srow * BK + (lane & 3) * 8;
    bf16_t* ldsB = Bs + srow * BK + (lane & 3) * 8;

    // 16x16x32 fragment addressing:
    //  A: lane holds A[m=lane&15][k=(lane>>4)*8+j]; B mirrored ([n][k] in Bs)
    //  C/D: col=lane&15, row=(lane>>4)*4+reg   [m89/m91-verified]
    const int frm = lane & 15;
    const int jch = lane >> 4;           // K-chunk 0..3
    const int sw = (lane >> 1) & 3;      // ((row&15)>>1)&3
    const int choff = ((jch ^ sw) * 8);  // swizzled physical chunk offset

    f32x4 acc[4][4] = {};

    for (int kt = 0; kt < KITERS; ++kt) {
        const int k0 = kt * BK;
        async16(Ag + k0, ldsA);
        async16(Ag + k0 + (size_t)128 * K_DIM, ldsA + 128 * BK);
        async16(Bg + k0, ldsB);
        __syncthreads();

        bf16x8 af[4], bv[4];
#pragma unroll
        for (int i = 0; i < 4; ++i)
            af[i] = *(const bf16x8*)&As[(wm * 64 + i * 16 + frm) * BK + choff];
#pragma unroll
        for (int j = 0; j < 4; ++j)
            bv[j] = *(const bf16x8*)&Bs[(wn * 64 + j * 16 + frm) * BK + choff];
#pragma unroll
        for (int i = 0; i < 4; ++i)
#pragma unroll
            for (int j = 0; j < 4; ++j)
                acc[i][j] = __builtin_amdgcn_mfma_f32_16x16x32_bf16(af[i], bv[j], acc[i][j], 0, 0, 0);
        __syncthreads();
    }

    // epilogue (fp32 stores)
    const float sc = powf(sqrtf((float)N_DIM) / logf(1.0f + (float)N_DIM), alpha[0]);
    float wsq_c[4], bias_c[4];
#pragma unroll
    for (int j = 0; j < 4; ++j) {
        const int col = bn * BN + wn * 64 + j * 16 + frm;
        wsq_c[j] = wsq[col];
        bias_c[j] = bias[col];
    }
#pragma unroll
    for (int i = 0; i < 4; ++i) {
#pragma unroll
        for (int r = 0; r < 4; ++r) {
            const int row = bm * BM + wm * 64 + i * 16 + (lane >> 4) * 4 + r;
            const float xs = xsq[row];
            float* orow = out + (size_t)row * N_DIM + bn * BN + wn * 64 + frm;
#pragma unroll
            for (int j = 0; j < 4; ++j) {
                const float y = acc[i][j][r];
                const float d = xs + wsq_c[j] - 2.0f * y + 1e-6f;
                orow[j * 16] = (y * y) / d * sc + bias_c[j];
            }
        }
    }
}

extern "C" void kernel_launch(void* const* d_in, const int* in_sizes, int n_in,
                              void* d_out, int out_size, void* d_ws, size_t ws_size,
                              hipStream_t stream) {
    (void)in_sizes; (void)n_in; (void)out_size; (void)ws_size;
    const float* x = (const float*)d_in[0];      // [16384, 2048] fp32
    const float* w = (const float*)d_in[1];      // [2048, 2048] fp32
    const float* alpha = (const float*)d_in[2];  // [1] fp32
    const float* bias = (const float*)d_in[3];   // [2048] fp32
    float* out = (float*)d_out;                  // [16384, 2048] fp32

    // ws layout: xb (33.5M bf16), wb (4.2M bf16), xsq (16384 f32), wsq (2048 f32)
    bf16_t* xb = (bf16_t*)d_ws;
    bf16_t* wb = xb + (size_t)M_DIM * K_DIM;
    float* xsq = (float*)(wb + (size_t)N_DIM * K_DIM);
    float* wsq = xsq + M_DIM;

    prep_convert<<<M_DIM + N_DIM, 256, 0, stream>>>(x, w, xb, wb, xsq, wsq);
    yat_gemm<<<(M_DIM / BM) * (N_DIM / BN), 512, 0, stream>>>(xb, wb, xsq, wsq, bias, alpha, out);
}